// Round 1
// baseline (6500.170 us; speedup 1.0000x reference)
//
#include <hip/hip_runtime.h>
#include <hip/hip_bf16.h>
#include <math.h>

#define L_SEQ 2048
#define Dm    512
#define DI    1024
#define Nst   16
#define Kc    4
#define Rr    32
#define NL    4

// ---------------- helpers ----------------
__device__ __forceinline__ float act_softplus(float x) {
    // log(1+exp(x)) stable
    return fmaxf(x, 0.f) + log1pf(__expf(-fabsf(x)));
}
__device__ __forceinline__ float act_gelu(float x) {
    // jax.nn.gelu default: approximate=True (tanh form)
    float c = 0.7978845608028654f * (x + 0.044715f * x * x * x);
    float t = 1.f - 2.f / (__expf(2.f * c) + 1.f);   // tanh(c)
    return 0.5f * x * (1.f + t);
}
__device__ __forceinline__ float silu_(float x) {
    return x / (1.f + __expf(-x));
}

// ---------------- LayerNorm (rows of 512) ----------------
__global__ __launch_bounds__(256) void ln_kernel(const float* __restrict__ x,
    const float* __restrict__ w, const float* __restrict__ b, float* __restrict__ y)
{
    int row = blockIdx.x;
    int i0 = threadIdx.x, i1 = threadIdx.x + 256;
    const float* xr = x + (size_t)row * Dm;
    float v0 = xr[i0], v1 = xr[i1];
    float s = v0 + v1, ss = v0 * v0 + v1 * v1;
    for (int off = 32; off; off >>= 1) { s += __shfl_down(s, off); ss += __shfl_down(ss, off); }
    __shared__ float red[10];
    int wid = threadIdx.x >> 6;
    if ((threadIdx.x & 63) == 0) { red[wid] = s; red[4 + wid] = ss; }
    __syncthreads();
    if (threadIdx.x == 0) {
        float S = red[0] + red[1] + red[2] + red[3];
        float SS = red[4] + red[5] + red[6] + red[7];
        float mu = S * (1.f / Dm);
        float var = SS * (1.f / Dm) - mu * mu;
        red[8] = mu; red[9] = rsqrtf(var + 1e-5f);
    }
    __syncthreads();
    float mu = red[8], rs = red[9];
    float* yr = y + (size_t)row * Dm;
    yr[i0] = (v0 - mu) * rs * w[i0] + b[i0];
    yr[i1] = (v1 - mu) * rs * w[i1] + b[i1];
}

// ---------------- residual add + RMSNorm ----------------
__global__ __launch_bounds__(256) void add_rms_kernel(const float* __restrict__ a,
    const float* __restrict__ bsrc, float* __restrict__ sum_out,
    const float* __restrict__ w, float* __restrict__ rms_out)
{
    int row = blockIdx.x;
    int i0 = threadIdx.x, i1 = threadIdx.x + 256;
    size_t base = (size_t)row * Dm;
    float v0 = a[base + i0], v1 = a[base + i1];
    if (bsrc) { v0 += bsrc[base + i0]; v1 += bsrc[base + i1]; }
    sum_out[base + i0] = v0; sum_out[base + i1] = v1;
    float ss = v0 * v0 + v1 * v1;
    for (int off = 32; off; off >>= 1) ss += __shfl_down(ss, off);
    __shared__ float red[5];
    if ((threadIdx.x & 63) == 0) red[threadIdx.x >> 6] = ss;
    __syncthreads();
    if (threadIdx.x == 0) red[4] = rsqrtf((red[0] + red[1] + red[2] + red[3]) * (1.f / Dm) + 1e-5f);
    __syncthreads();
    float rs = red[4];
    rms_out[base + i0] = v0 * rs * w[i0];
    rms_out[base + i1] = v1 * rs * w[i1];
}

// ---------------- final: hout = shortcut + RMS(h+res)*w ----------------
__global__ __launch_bounds__(256) void final_merge_kernel(const float* __restrict__ h,
    const float* __restrict__ res, const float* __restrict__ shortcut,
    const float* __restrict__ w, float* __restrict__ hout)
{
    int row = blockIdx.x;
    int i0 = threadIdx.x, i1 = threadIdx.x + 256;
    size_t base = (size_t)row * Dm;
    float v0 = h[base + i0] + res[base + i0];
    float v1 = h[base + i1] + res[base + i1];
    float ss = v0 * v0 + v1 * v1;
    for (int off = 32; off; off >>= 1) ss += __shfl_down(ss, off);
    __shared__ float red[5];
    if ((threadIdx.x & 63) == 0) red[threadIdx.x >> 6] = ss;
    __syncthreads();
    if (threadIdx.x == 0) red[4] = rsqrtf((red[0] + red[1] + red[2] + red[3]) * (1.f / Dm) + 1e-5f);
    __syncthreads();
    float rs = red[4];
    hout[base + i0] = shortcut[base + i0] + v0 * rs * w[i0];
    hout[base + i1] = shortcut[base + i1] + v1 * rs * w[i1];
}

// ---------------- GEMM: C(M,N) = A(M,K; lda) * W(N,K)^T  (+bias, act, +add) ----------------
// act: 0 none, 1 softplus, 2 gelu
__global__ __launch_bounds__(256) void gemm_nt(const float* __restrict__ A, int lda,
    const float* __restrict__ W, float* __restrict__ C,
    int M, int N, int Kd,
    const float* __restrict__ bias, const float* __restrict__ addsrc, int act)
{
    __shared__ float As[64][17];
    __shared__ float Ws[64][17];
    int tid = threadIdx.x;
    int tx = tid & 15, ty = tid >> 4;
    int bm = blockIdx.y * 64, bn = blockIdx.x * 64;
    int lrow = tid >> 2, lcol = (tid & 3) << 2;
    const float* Ap = A + (size_t)(bm + lrow) * lda + lcol;
    const float* Wp = W + (size_t)(bn + lrow) * Kd + lcol;
    float acc[4][4] = {};
    for (int k0 = 0; k0 < Kd; k0 += 16) {
        float4 av = *(const float4*)(Ap + k0);
        float4 wv = *(const float4*)(Wp + k0);
        As[lrow][lcol + 0] = av.x; As[lrow][lcol + 1] = av.y;
        As[lrow][lcol + 2] = av.z; As[lrow][lcol + 3] = av.w;
        Ws[lrow][lcol + 0] = wv.x; Ws[lrow][lcol + 1] = wv.y;
        Ws[lrow][lcol + 2] = wv.z; Ws[lrow][lcol + 3] = wv.w;
        __syncthreads();
        #pragma unroll
        for (int k = 0; k < 16; ++k) {
            float a[4], wr[4];
            #pragma unroll
            for (int i = 0; i < 4; ++i) a[i] = As[ty * 4 + i][k];
            #pragma unroll
            for (int j = 0; j < 4; ++j) wr[j] = Ws[tx * 4 + j][k];
            #pragma unroll
            for (int i = 0; i < 4; ++i)
                #pragma unroll
                for (int j = 0; j < 4; ++j)
                    acc[i][j] = fmaf(a[i], wr[j], acc[i][j]);
        }
        __syncthreads();
    }
    #pragma unroll
    for (int i = 0; i < 4; ++i) {
        int row = bm + ty * 4 + i;
        #pragma unroll
        for (int j = 0; j < 4; ++j) {
            int col = bn + tx * 4 + j;
            float v = acc[i][j];
            if (bias) v += bias[col];
            if (act == 1) v = act_softplus(v);
            else if (act == 2) v = act_gelu(v);
            if (addsrc) v += addsrc[(size_t)row * N + col];
            C[(size_t)row * N + col] = v;
        }
    }
}

// ---------------- causal depthwise conv (K=4) + silu ----------------
__global__ __launch_bounds__(256) void conv_silu_kernel(const float* __restrict__ xz,
    const float* __restrict__ cw, const float* __restrict__ cb, float* __restrict__ xc)
{
    int idx = blockIdx.x * 256 + threadIdx.x;   // over L*DI
    int d = idx & (DI - 1);
    int t = idx >> 10;
    float acc = cb[d];
    #pragma unroll
    for (int k = 0; k < 4; ++k) {
        int tt = t + k - 3;
        if (tt >= 0) acc = fmaf(cw[d * 4 + k], xz[(size_t)tt * (2 * DI) + d], acc);
    }
    xc[idx] = silu_(acc);
}

// ---------------- sequential SSM scan, (d,n)-parallel ----------------
// lane layout: n = tid&15, d = tid>>4.  y gated by silu(z) on store.
__global__ __launch_bounds__(1024) void ssm_scan_kernel(
    const float* __restrict__ delta, const float* __restrict__ u,
    const float* __restrict__ dbc, const float* __restrict__ A_log,
    const float* __restrict__ Dp, const float* __restrict__ xz,
    float* __restrict__ y)
{
    int tid = blockIdx.x * 1024 + threadIdx.x;
    int n = tid & 15;
    int d = tid >> 4;
    float Aval = -__expf(A_log[d * Nst + n]);
    float Dval = Dp[d];
    float hst = 0.f;
    float dt_ = delta[d], u_ = u[d];
    float b_ = dbc[32 + n], c_ = dbc[48 + n];
    for (int t = 0; t < L_SEQ; ++t) {
        float dt_n = 0.f, u_n = 0.f, b_n = 0.f, c_n = 0.f;
        if (t + 1 < L_SEQ) {
            size_t o = (size_t)(t + 1) * DI + d;
            dt_n = delta[o]; u_n = u[o];
            b_n = dbc[(t + 1) * 64 + 32 + n];
            c_n = dbc[(t + 1) * 64 + 48 + n];
        }
        float dA = __expf(dt_ * Aval);
        hst = fmaf(dA, hst, (dt_ * u_) * b_);
        float py = hst * c_;
        py += __shfl_down(py, 8, 16);
        py += __shfl_down(py, 4, 16);
        py += __shfl_down(py, 2, 16);
        py += __shfl_down(py, 1, 16);
        if (n == 0) {
            float z = xz[(size_t)t * (2 * DI) + DI + d];
            y[(size_t)t * DI + d] = (py + u_ * Dval) * silu_(z);
        }
        dt_ = dt_n; u_ = u_n; b_ = b_n; c_ = c_n;
    }
}

extern "C" void kernel_launch(void* const* d_in, const int* in_sizes, int n_in,
                              void* d_out, int out_size, void* d_ws, size_t ws_size,
                              hipStream_t stream)
{
    const float* hidden     = (const float*)d_in[0];
    const float* ln1_w      = (const float*)d_in[1];
    const float* ln1_b      = (const float*)d_in[2];
    const float* in_proj_w  = (const float*)d_in[3];
    const float* conv_w     = (const float*)d_in[4];
    const float* conv_b     = (const float*)d_in[5];
    const float* x_proj_w   = (const float*)d_in[6];
    const float* dt_proj_w  = (const float*)d_in[7];
    const float* dt_proj_b  = (const float*)d_in[8];
    const float* A_log      = (const float*)d_in[9];
    const float* D_param    = (const float*)d_in[10];
    const float* out_proj_w = (const float*)d_in[11];
    const float* block_norm_w = (const float*)d_in[12];
    const float* norm_f_w   = (const float*)d_in[13];
    const float* ln2_w      = (const float*)d_in[14];
    const float* ln2_b      = (const float*)d_in[15];
    const float* fc1_w      = (const float*)d_in[16];
    const float* fc1_b      = (const float*)d_in[17];
    const float* fc2_w      = (const float*)d_in[18];
    const float* fc2_b      = (const float*)d_in[19];

    float* ws = (float*)d_ws;
    const size_t M1 = 1u << 20;          // 1M floats = L*Dm
    float* h     = ws + 0 * M1;
    float* res   = ws + 1 * M1;
    float* hn    = ws + 2 * M1;          // also reused as ln2 output
    float* hout  = ws + 3 * M1;
    float* xz    = ws + 4 * M1;          // 4M floats; reused as MLP t1
    float* xc    = ws + 8 * M1;          // 2M floats
    float* delta = ws + 10 * M1;         // 2M floats
    float* yb    = ws + 12 * M1;         // 2M floats
    float* dbc   = ws + 14 * M1;         // 131072 floats
    float* out   = (float*)d_out;

    ln_kernel<<<L_SEQ, 256, 0, stream>>>(hidden, ln1_w, ln1_b, h);

    for (int i = 0; i < NL; ++i) {
        add_rms_kernel<<<L_SEQ, 256, 0, stream>>>(h, i ? res : nullptr, res,
                                                  block_norm_w + i * Dm, hn);
        dim3 g1(2 * DI / 64, L_SEQ / 64);
        gemm_nt<<<g1, 256, 0, stream>>>(hn, Dm, in_proj_w + (size_t)i * 2 * DI * Dm, xz,
                                        L_SEQ, 2 * DI, Dm, nullptr, nullptr, 0);
        conv_silu_kernel<<<(L_SEQ * DI) / 256, 256, 0, stream>>>(
            xz, conv_w + i * DI * Kc, conv_b + i * DI, xc);
        dim3 g2(64 / 64, L_SEQ / 64);
        gemm_nt<<<g2, 256, 0, stream>>>(xc, DI, x_proj_w + (size_t)i * 64 * DI, dbc,
                                        L_SEQ, 64, DI, nullptr, nullptr, 0);
        dim3 g3(DI / 64, L_SEQ / 64);
        gemm_nt<<<g3, 256, 0, stream>>>(dbc, 64, dt_proj_w + (size_t)i * DI * Rr, delta,
                                        L_SEQ, DI, Rr, dt_proj_b + i * DI, nullptr, 1);
        ssm_scan_kernel<<<16, 1024, 0, stream>>>(delta, xc, dbc,
                                        A_log + (size_t)i * DI * Nst,
                                        D_param + i * DI, xz, yb);
        dim3 g4(Dm / 64, L_SEQ / 64);
        gemm_nt<<<g4, 256, 0, stream>>>(yb, DI, out_proj_w + (size_t)i * Dm * DI, h,
                                        L_SEQ, Dm, DI, nullptr, nullptr, 0);
    }

    final_merge_kernel<<<L_SEQ, 256, 0, stream>>>(h, res, hidden, norm_f_w, hout);
    ln_kernel<<<L_SEQ, 256, 0, stream>>>(hout, ln2_w, ln2_b, hn);
    dim3 g5(2048 / 64, L_SEQ / 64);
    gemm_nt<<<g5, 256, 0, stream>>>(hn, Dm, fc1_w, xz, L_SEQ, 2048, Dm,
                                    fc1_b, nullptr, 2);
    dim3 g6(Dm / 64, L_SEQ / 64);
    gemm_nt<<<g6, 256, 0, stream>>>(xz, 2048, fc2_w, out, L_SEQ, Dm, 2048,
                                    fc2_b, hout, 0);
}

// Round 2
// 1591.490 us; speedup vs baseline: 4.0843x; 4.0843x over previous
//
#include <hip/hip_runtime.h>
#include <hip/hip_bf16.h>
#include <math.h>

#define L_SEQ 2048
#define Dm    512
#define DI    1024
#define Nst   16
#define Kc    4
#define Rr    32
#define NL    4
#define CH    64
#define LC    (L_SEQ / CH)   // 32

// ---------------- helpers ----------------
__device__ __forceinline__ float act_softplus(float x) {
    return fmaxf(x, 0.f) + log1pf(__expf(-fabsf(x)));
}
__device__ __forceinline__ float act_gelu(float x) {
    float c = 0.7978845608028654f * (x + 0.044715f * x * x * x);
    float t = 1.f - 2.f / (__expf(2.f * c) + 1.f);   // tanh(c)
    return 0.5f * x * (1.f + t);
}
__device__ __forceinline__ float silu_(float x) {
    return x / (1.f + __expf(-x));
}

// ---------------- LayerNorm (rows of 512) ----------------
__global__ __launch_bounds__(256) void ln_kernel(const float* __restrict__ x,
    const float* __restrict__ w, const float* __restrict__ b, float* __restrict__ y)
{
    int row = blockIdx.x;
    int i0 = threadIdx.x, i1 = threadIdx.x + 256;
    const float* xr = x + (size_t)row * Dm;
    float v0 = xr[i0], v1 = xr[i1];
    float s = v0 + v1, ss = v0 * v0 + v1 * v1;
    for (int off = 32; off; off >>= 1) { s += __shfl_down(s, off); ss += __shfl_down(ss, off); }
    __shared__ float red[10];
    int wid = threadIdx.x >> 6;
    if ((threadIdx.x & 63) == 0) { red[wid] = s; red[4 + wid] = ss; }
    __syncthreads();
    if (threadIdx.x == 0) {
        float S = red[0] + red[1] + red[2] + red[3];
        float SS = red[4] + red[5] + red[6] + red[7];
        float mu = S * (1.f / Dm);
        float var = SS * (1.f / Dm) - mu * mu;
        red[8] = mu; red[9] = rsqrtf(var + 1e-5f);
    }
    __syncthreads();
    float mu = red[8], rs = red[9];
    float* yr = y + (size_t)row * Dm;
    yr[i0] = (v0 - mu) * rs * w[i0] + b[i0];
    yr[i1] = (v1 - mu) * rs * w[i1] + b[i1];
}

// ---------------- residual add + RMSNorm ----------------
__global__ __launch_bounds__(256) void add_rms_kernel(const float* __restrict__ a,
    const float* __restrict__ bsrc, float* __restrict__ sum_out,
    const float* __restrict__ w, float* __restrict__ rms_out)
{
    int row = blockIdx.x;
    int i0 = threadIdx.x, i1 = threadIdx.x + 256;
    size_t base = (size_t)row * Dm;
    float v0 = a[base + i0], v1 = a[base + i1];
    if (bsrc) { v0 += bsrc[base + i0]; v1 += bsrc[base + i1]; }
    sum_out[base + i0] = v0; sum_out[base + i1] = v1;
    float ss = v0 * v0 + v1 * v1;
    for (int off = 32; off; off >>= 1) ss += __shfl_down(ss, off);
    __shared__ float red[5];
    if ((threadIdx.x & 63) == 0) red[threadIdx.x >> 6] = ss;
    __syncthreads();
    if (threadIdx.x == 0) red[4] = rsqrtf((red[0] + red[1] + red[2] + red[3]) * (1.f / Dm) + 1e-5f);
    __syncthreads();
    float rs = red[4];
    rms_out[base + i0] = v0 * rs * w[i0];
    rms_out[base + i1] = v1 * rs * w[i1];
}

// ---------------- final: hout = shortcut + RMS(h+res)*w ----------------
__global__ __launch_bounds__(256) void final_merge_kernel(const float* __restrict__ h,
    const float* __restrict__ res, const float* __restrict__ shortcut,
    const float* __restrict__ w, float* __restrict__ hout)
{
    int row = blockIdx.x;
    int i0 = threadIdx.x, i1 = threadIdx.x + 256;
    size_t base = (size_t)row * Dm;
    float v0 = h[base + i0] + res[base + i0];
    float v1 = h[base + i1] + res[base + i1];
    float ss = v0 * v0 + v1 * v1;
    for (int off = 32; off; off >>= 1) ss += __shfl_down(ss, off);
    __shared__ float red[5];
    if ((threadIdx.x & 63) == 0) red[threadIdx.x >> 6] = ss;
    __syncthreads();
    if (threadIdx.x == 0) red[4] = rsqrtf((red[0] + red[1] + red[2] + red[3]) * (1.f / Dm) + 1e-5f);
    __syncthreads();
    float rs = red[4];
    hout[base + i0] = shortcut[base + i0] + v0 * rs * w[i0];
    hout[base + i1] = shortcut[base + i1] + v1 * rs * w[i1];
}

// ---------------- GEMM: C(M,N) = A(M,K; lda) * W(N,K)^T  (+bias, act, +add) ----------------
__global__ __launch_bounds__(256) void gemm_nt(const float* __restrict__ A, int lda,
    const float* __restrict__ W, float* __restrict__ C,
    int M, int N, int Kd,
    const float* __restrict__ bias, const float* __restrict__ addsrc, int act)
{
    __shared__ float As[64][17];
    __shared__ float Ws[64][17];
    int tid = threadIdx.x;
    int tx = tid & 15, ty = tid >> 4;
    int bm = blockIdx.y * 64, bn = blockIdx.x * 64;
    int lrow = tid >> 2, lcol = (tid & 3) << 2;
    const float* Ap = A + (size_t)(bm + lrow) * lda + lcol;
    const float* Wp = W + (size_t)(bn + lrow) * Kd + lcol;
    float acc[4][4] = {};
    for (int k0 = 0; k0 < Kd; k0 += 16) {
        float4 av = *(const float4*)(Ap + k0);
        float4 wv = *(const float4*)(Wp + k0);
        As[lrow][lcol + 0] = av.x; As[lrow][lcol + 1] = av.y;
        As[lrow][lcol + 2] = av.z; As[lrow][lcol + 3] = av.w;
        Ws[lrow][lcol + 0] = wv.x; Ws[lrow][lcol + 1] = wv.y;
        Ws[lrow][lcol + 2] = wv.z; Ws[lrow][lcol + 3] = wv.w;
        __syncthreads();
        #pragma unroll
        for (int k = 0; k < 16; ++k) {
            float a[4], wr[4];
            #pragma unroll
            for (int i = 0; i < 4; ++i) a[i] = As[ty * 4 + i][k];
            #pragma unroll
            for (int j = 0; j < 4; ++j) wr[j] = Ws[tx * 4 + j][k];
            #pragma unroll
            for (int i = 0; i < 4; ++i)
                #pragma unroll
                for (int j = 0; j < 4; ++j)
                    acc[i][j] = fmaf(a[i], wr[j], acc[i][j]);
        }
        __syncthreads();
    }
    #pragma unroll
    for (int i = 0; i < 4; ++i) {
        int row = bm + ty * 4 + i;
        #pragma unroll
        for (int j = 0; j < 4; ++j) {
            int col = bn + tx * 4 + j;
            float v = acc[i][j];
            if (bias) v += bias[col];
            if (act == 1) v = act_softplus(v);
            else if (act == 2) v = act_gelu(v);
            if (addsrc) v += addsrc[(size_t)row * N + col];
            C[(size_t)row * N + col] = v;
        }
    }
}

// ---------------- causal depthwise conv (K=4) + silu ----------------
__global__ __launch_bounds__(256) void conv_silu_kernel(const float* __restrict__ xz,
    const float* __restrict__ cw, const float* __restrict__ cb, float* __restrict__ xc)
{
    int idx = blockIdx.x * 256 + threadIdx.x;   // over L*DI
    int d = idx & (DI - 1);
    int t = idx >> 10;
    float acc = cb[d];
    #pragma unroll
    for (int k = 0; k < 4; ++k) {
        int tt = t + k - 3;
        if (tt >= 0) acc = fmaf(cw[d * 4 + k], xz[(size_t)tt * (2 * DI) + d], acc);
    }
    xc[idx] = silu_(acc);
}

// ---------------- 3-phase chunked SSM scan ----------------
// Phase A: per-(d,n,chunk) local scan with h_in = 0; record (prod dA, h_end).
__global__ __launch_bounds__(256) void scan_chunk_kernel(
    const float* __restrict__ delta, const float* __restrict__ u,
    const float* __restrict__ dbc, const float* __restrict__ A_log,
    float* __restrict__ hend, float* __restrict__ aprod)
{
    int n = threadIdx.x & 15, dl = threadIdx.x >> 4;
    int c = blockIdx.x;
    int d = blockIdx.y * 16 + dl;
    float Aval = -__expf(A_log[d * Nst + n]);
    float h = 0.f, ap = 1.f;
    int t0 = c * LC;
    #pragma unroll 4
    for (int t = t0; t < t0 + LC; ++t) {
        float dt_ = delta[(size_t)t * DI + d];
        float u_  = u[(size_t)t * DI + d];
        float b_  = dbc[t * 64 + 32 + n];
        float dA = __expf(dt_ * Aval);
        h = fmaf(dA, h, dt_ * u_ * b_);
        ap *= dA;
    }
    size_t j = (size_t)c * (DI * Nst) + d * Nst + n;
    hend[j] = h;
    aprod[j] = ap;
}

// Phase B: sequential combine over chunks per (d,n): record each chunk's h_in.
__global__ __launch_bounds__(256) void chunk_prefix_kernel(
    const float* __restrict__ hend, const float* __restrict__ aprod,
    float* __restrict__ hin)
{
    int j = blockIdx.x * 256 + threadIdx.x;   // over DI*Nst
    float h = 0.f;
    for (int c = 0; c < CH; ++c) {
        size_t o = (size_t)c * (DI * Nst) + j;
        hin[o] = h;
        h = fmaf(aprod[o], h, hend[o]);
    }
}

// Phase C: re-scan each chunk from its true h_in; contract with C over n;
// gate with silu(z); add u*D; write y.
__global__ __launch_bounds__(256) void scan_apply_kernel(
    const float* __restrict__ delta, const float* __restrict__ u,
    const float* __restrict__ dbc, const float* __restrict__ A_log,
    const float* __restrict__ Dp, const float* __restrict__ xz,
    const float* __restrict__ hin, float* __restrict__ y)
{
    int n = threadIdx.x & 15, dl = threadIdx.x >> 4;
    int c = blockIdx.x;
    int d = blockIdx.y * 16 + dl;
    float Aval = -__expf(A_log[d * Nst + n]);
    float Dval = Dp[d];
    float h = hin[(size_t)c * (DI * Nst) + d * Nst + n];
    int t0 = c * LC;
    for (int t = t0; t < t0 + LC; ++t) {
        float dt_ = delta[(size_t)t * DI + d];
        float u_  = u[(size_t)t * DI + d];
        float b_  = dbc[t * 64 + 32 + n];
        float c_  = dbc[t * 64 + 48 + n];
        float dA = __expf(dt_ * Aval);
        h = fmaf(dA, h, dt_ * u_ * b_);
        float py = h * c_;
        py += __shfl_down(py, 8, 16);
        py += __shfl_down(py, 4, 16);
        py += __shfl_down(py, 2, 16);
        py += __shfl_down(py, 1, 16);
        if (n == 0) {
            float z = xz[(size_t)t * (2 * DI) + DI + d];
            y[(size_t)t * DI + d] = (py + u_ * Dval) * silu_(z);
        }
    }
}

extern "C" void kernel_launch(void* const* d_in, const int* in_sizes, int n_in,
                              void* d_out, int out_size, void* d_ws, size_t ws_size,
                              hipStream_t stream)
{
    const float* hidden     = (const float*)d_in[0];
    const float* ln1_w      = (const float*)d_in[1];
    const float* ln1_b      = (const float*)d_in[2];
    const float* in_proj_w  = (const float*)d_in[3];
    const float* conv_w     = (const float*)d_in[4];
    const float* conv_b     = (const float*)d_in[5];
    const float* x_proj_w   = (const float*)d_in[6];
    const float* dt_proj_w  = (const float*)d_in[7];
    const float* dt_proj_b  = (const float*)d_in[8];
    const float* A_log      = (const float*)d_in[9];
    const float* D_param    = (const float*)d_in[10];
    const float* out_proj_w = (const float*)d_in[11];
    const float* block_norm_w = (const float*)d_in[12];
    const float* norm_f_w   = (const float*)d_in[13];
    const float* ln2_w      = (const float*)d_in[14];
    const float* ln2_b      = (const float*)d_in[15];
    const float* fc1_w      = (const float*)d_in[16];
    const float* fc1_b      = (const float*)d_in[17];
    const float* fc2_w      = (const float*)d_in[18];
    const float* fc2_b      = (const float*)d_in[19];

    float* ws = (float*)d_ws;
    const size_t M1 = 1u << 20;          // 1M floats = L*Dm
    float* h     = ws + 0 * M1;          // layer output; doubles as hend during scan
    float* res   = ws + 1 * M1;
    float* hn    = ws + 2 * M1;          // rms out; free after in_proj -> doubles as hin
    float* hout  = ws + 3 * M1;          // free until final_merge -> doubles as aprod
    float* xz    = ws + 4 * M1;          // 4M floats; reused as MLP t1
    float* xc    = ws + 8 * M1;          // 2M floats
    float* delta = ws + 10 * M1;         // 2M floats
    float* yb    = ws + 12 * M1;         // 2M floats
    float* dbc   = ws + 14 * M1;         // 131072 floats
    float* out   = (float*)d_out;

    ln_kernel<<<L_SEQ, 256, 0, stream>>>(hidden, ln1_w, ln1_b, h);

    dim3 gscan(CH, DI / 16);             // 64 x 64 blocks of 256
    for (int i = 0; i < NL; ++i) {
        add_rms_kernel<<<L_SEQ, 256, 0, stream>>>(h, i ? res : nullptr, res,
                                                  block_norm_w + i * Dm, hn);
        dim3 g1(2 * DI / 64, L_SEQ / 64);
        gemm_nt<<<g1, 256, 0, stream>>>(hn, Dm, in_proj_w + (size_t)i * 2 * DI * Dm, xz,
                                        L_SEQ, 2 * DI, Dm, nullptr, nullptr, 0);
        conv_silu_kernel<<<(L_SEQ * DI) / 256, 256, 0, stream>>>(
            xz, conv_w + i * DI * Kc, conv_b + i * DI, xc);
        dim3 g2(64 / 64, L_SEQ / 64);
        gemm_nt<<<g2, 256, 0, stream>>>(xc, DI, x_proj_w + (size_t)i * 64 * DI, dbc,
                                        L_SEQ, 64, DI, nullptr, nullptr, 0);
        dim3 g3(DI / 64, L_SEQ / 64);
        gemm_nt<<<g3, 256, 0, stream>>>(dbc, 64, dt_proj_w + (size_t)i * DI * Rr, delta,
                                        L_SEQ, DI, Rr, dt_proj_b + i * DI, nullptr, 1);

        // 3-phase chunked scan (hend=h, aprod=hout, hin=hn: all dead here)
        scan_chunk_kernel<<<gscan, 256, 0, stream>>>(delta, xc, dbc,
                                        A_log + (size_t)i * DI * Nst, h, hout);
        chunk_prefix_kernel<<<(DI * Nst) / 256, 256, 0, stream>>>(h, hout, hn);
        scan_apply_kernel<<<gscan, 256, 0, stream>>>(delta, xc, dbc,
                                        A_log + (size_t)i * DI * Nst,
                                        D_param + i * DI, xz, hn, yb);

        dim3 g4(Dm / 64, L_SEQ / 64);
        gemm_nt<<<g4, 256, 0, stream>>>(yb, DI, out_proj_w + (size_t)i * Dm * DI, h,
                                        L_SEQ, Dm, DI, nullptr, nullptr, 0);
    }

    final_merge_kernel<<<L_SEQ, 256, 0, stream>>>(h, res, hidden, norm_f_w, hout);
    ln_kernel<<<L_SEQ, 256, 0, stream>>>(hout, ln2_w, ln2_b, hn);
    dim3 g5(2048 / 64, L_SEQ / 64);
    gemm_nt<<<g5, 256, 0, stream>>>(hn, Dm, fc1_w, xz, L_SEQ, 2048, Dm,
                                    fc1_b, nullptr, 2);
    dim3 g6(Dm / 64, L_SEQ / 64);
    gemm_nt<<<g6, 256, 0, stream>>>(xz, 2048, fc2_w, out, L_SEQ, Dm, 2048,
                                    fc2_b, hout, 0);
}

// Round 3
// 617.405 us; speedup vs baseline: 10.5282x; 2.5777x over previous
//
#include <hip/hip_runtime.h>
#include <hip/hip_bf16.h>
#include <math.h>

#define L_SEQ 2048
#define Dm    512
#define DI    1024
#define Nst   16
#define Kc    4
#define Rr    32
#define NL    4
#define CH    64
#define LC    (L_SEQ / CH)   // 32

typedef __attribute__((ext_vector_type(8))) short bf16x8;
typedef __attribute__((ext_vector_type(4))) float f32x4;

// ---------------- helpers ----------------
__device__ __forceinline__ float act_softplus(float x) {
    return fmaxf(x, 0.f) + log1pf(__expf(-fabsf(x)));
}
__device__ __forceinline__ float act_gelu(float x) {
    float c = 0.7978845608028654f * (x + 0.044715f * x * x * x);
    float t = 1.f - 2.f / (__expf(2.f * c) + 1.f);   // tanh(c)
    return 0.5f * x * (1.f + t);
}
__device__ __forceinline__ float silu_(float x) {
    return x / (1.f + __expf(-x));
}
__device__ __forceinline__ ushort f2bf(float f) {
    union { float f; unsigned u; } c; c.f = f;
    unsigned r = c.u + 0x7fffu + ((c.u >> 16) & 1u);
    return (ushort)(r >> 16);
}
__device__ __forceinline__ float bf2f(ushort u) {
    union { unsigned u; float f; } c; c.u = ((unsigned)u) << 16;
    return c.f;
}

// ---------------- weight cast f32 -> bf16 ----------------
__global__ __launch_bounds__(256) void cast_w_kernel(const float* __restrict__ src,
    ushort* __restrict__ dst, int n4)
{
    int i = blockIdx.x * 256 + threadIdx.x;
    if (i >= n4) return;
    float4 v = ((const float4*)src)[i];
    ushort4 o;
    o.x = f2bf(v.x); o.y = f2bf(v.y); o.z = f2bf(v.z); o.w = f2bf(v.w);
    ((ushort4*)dst)[i] = o;
}

// ---------------- LayerNorm (rows of 512), fp32 or bf16 out ----------------
__global__ __launch_bounds__(256) void ln_kernel(const float* __restrict__ x,
    const float* __restrict__ w, const float* __restrict__ b,
    float* __restrict__ yf, ushort* __restrict__ yb16)
{
    int row = blockIdx.x;
    int i0 = threadIdx.x, i1 = threadIdx.x + 256;
    const float* xr = x + (size_t)row * Dm;
    float v0 = xr[i0], v1 = xr[i1];
    float s = v0 + v1, ss = v0 * v0 + v1 * v1;
    for (int off = 32; off; off >>= 1) { s += __shfl_down(s, off); ss += __shfl_down(ss, off); }
    __shared__ float red[10];
    int wid = threadIdx.x >> 6;
    if ((threadIdx.x & 63) == 0) { red[wid] = s; red[4 + wid] = ss; }
    __syncthreads();
    if (threadIdx.x == 0) {
        float S = red[0] + red[1] + red[2] + red[3];
        float SS = red[4] + red[5] + red[6] + red[7];
        float mu = S * (1.f / Dm);
        float var = SS * (1.f / Dm) - mu * mu;
        red[8] = mu; red[9] = rsqrtf(var + 1e-5f);
    }
    __syncthreads();
    float mu = red[8], rs = red[9];
    float o0 = (v0 - mu) * rs * w[i0] + b[i0];
    float o1 = (v1 - mu) * rs * w[i1] + b[i1];
    if (yf) {
        yf[(size_t)row * Dm + i0] = o0;
        yf[(size_t)row * Dm + i1] = o1;
    } else {
        yb16[(size_t)row * Dm + i0] = f2bf(o0);
        yb16[(size_t)row * Dm + i1] = f2bf(o1);
    }
}

// ---------------- residual add + RMSNorm (sum fp32, rms out bf16) ----------------
__global__ __launch_bounds__(256) void add_rms_kernel(const float* __restrict__ a,
    const float* __restrict__ bsrc, float* __restrict__ sum_out,
    const float* __restrict__ w, ushort* __restrict__ rms_out)
{
    int row = blockIdx.x;
    int i0 = threadIdx.x, i1 = threadIdx.x + 256;
    size_t base = (size_t)row * Dm;
    float v0 = a[base + i0], v1 = a[base + i1];
    if (bsrc) { v0 += bsrc[base + i0]; v1 += bsrc[base + i1]; }
    sum_out[base + i0] = v0; sum_out[base + i1] = v1;
    float ss = v0 * v0 + v1 * v1;
    for (int off = 32; off; off >>= 1) ss += __shfl_down(ss, off);
    __shared__ float red[5];
    if ((threadIdx.x & 63) == 0) red[threadIdx.x >> 6] = ss;
    __syncthreads();
    if (threadIdx.x == 0) red[4] = rsqrtf((red[0] + red[1] + red[2] + red[3]) * (1.f / Dm) + 1e-5f);
    __syncthreads();
    float rs = red[4];
    rms_out[base + i0] = f2bf(v0 * rs * w[i0]);
    rms_out[base + i1] = f2bf(v1 * rs * w[i1]);
}

// ---------------- final: hout = shortcut + RMS(h+res)*w (fp32) ----------------
__global__ __launch_bounds__(256) void final_merge_kernel(const float* __restrict__ h,
    const float* __restrict__ res, const float* __restrict__ shortcut,
    const float* __restrict__ w, float* __restrict__ hout)
{
    int row = blockIdx.x;
    int i0 = threadIdx.x, i1 = threadIdx.x + 256;
    size_t base = (size_t)row * Dm;
    float v0 = h[base + i0] + res[base + i0];
    float v1 = h[base + i1] + res[base + i1];
    float ss = v0 * v0 + v1 * v1;
    for (int off = 32; off; off >>= 1) ss += __shfl_down(ss, off);
    __shared__ float red[5];
    if ((threadIdx.x & 63) == 0) red[threadIdx.x >> 6] = ss;
    __syncthreads();
    if (threadIdx.x == 0) red[4] = rsqrtf((red[0] + red[1] + red[2] + red[3]) * (1.f / Dm) + 1e-5f);
    __syncthreads();
    float rs = red[4];
    hout[base + i0] = shortcut[base + i0] + v0 * rs * w[i0];
    hout[base + i1] = shortcut[base + i1] + v1 * rs * w[i1];
}

// ---------------- MFMA bf16 GEMM: C(M,N) = A(M,K) * W(N,K)^T ----------------
// EPI: 0 = f32 store; 1 = bf16 store; 2 = bias+gelu -> bf16;
//      3 = bias+softplus -> f32; 4 = bias+addsrc -> f32;
//      5 = f32 store (ldc=64) + bf16 copy of cols<32 to aux (ld 32)
template<int BM, int BN, int BK, int EPI>
__global__ __launch_bounds__(256) void gemm_mfma(
    const ushort* __restrict__ A, int lda,
    const ushort* __restrict__ W, int K,
    void* __restrict__ Cout, int ldc,
    const float* __restrict__ bias, const float* __restrict__ addsrc,
    ushort* __restrict__ aux)
{
    constexpr int ROWB  = BK * 2;            // row bytes in LDS tile
    constexpr int SMASK = (ROWB / 16) - 1;   // 16B slots per row - 1
    constexpr int KK    = BK / 32;           // mfma k-chunks per step
    constexpr int WM = BM / 2, WN = BN / 2;
    constexpr int FM = WM / 16, FN = WN / 16;
    constexpr int ISS_A = (BM * ROWB) / 4096;
    constexpr int ISS_W = (BN * ROWB) / 4096;

    __shared__ __align__(16) ushort As[BM * BK];
    __shared__ __align__(16) ushort Ws[BN * BK];

    int tid = threadIdx.x;
    int wave = tid >> 6, lane = tid & 63;
    int wr = wave >> 1, wc = wave & 1;
    int l16 = lane & 15, lk = lane >> 4;
    int bm = blockIdx.y * BM, bn = blockIdx.x * BN;

    // staging source pointers (swizzled source, linear LDS dest)
    const ushort* srcA[ISS_A];
    const ushort* srcW[ISS_W];
    #pragma unroll
    for (int s = 0; s < ISS_A; ++s) {
        int off = s * 4096 + wave * 1024 + lane * 16;   // byte in tile
        int row = off / ROWB;
        int slot = (off % ROWB) >> 4;
        int col = ((slot ^ (row & SMASK)) << 3);        // element
        srcA[s] = A + (size_t)(bm + row) * lda + col;
    }
    #pragma unroll
    for (int s = 0; s < ISS_W; ++s) {
        int off = s * 4096 + wave * 1024 + lane * 16;
        int row = off / ROWB;
        int slot = (off % ROWB) >> 4;
        int col = ((slot ^ (row & SMASK)) << 3);
        srcW[s] = W + (size_t)(bn + row) * K + col;
    }
    // swizzled ds_read element offsets
    int aoff[FM][KK], woff[FN][KK];
    #pragma unroll
    for (int i = 0; i < FM; ++i) {
        int row = wr * WM + i * 16 + l16;
        #pragma unroll
        for (int kk = 0; kk < KK; ++kk)
            aoff[i][kk] = row * BK + ((((kk << 2) | lk) ^ (row & SMASK)) << 3);
    }
    #pragma unroll
    for (int j = 0; j < FN; ++j) {
        int row = wc * WN + j * 16 + l16;
        #pragma unroll
        for (int kk = 0; kk < KK; ++kk)
            woff[j][kk] = row * BK + ((((kk << 2) | lk) ^ (row & SMASK)) << 3);
    }

    f32x4 acc[FM][FN] = {};

    for (int k0 = 0; k0 < K; k0 += BK) {
        #pragma unroll
        for (int s = 0; s < ISS_A; ++s)
            __builtin_amdgcn_global_load_lds(
                (const __attribute__((address_space(1))) void*)(srcA[s] + k0),
                (__attribute__((address_space(3))) void*)((char*)As + s * 4096 + wave * 1024),
                16, 0, 0);
        #pragma unroll
        for (int s = 0; s < ISS_W; ++s)
            __builtin_amdgcn_global_load_lds(
                (const __attribute__((address_space(1))) void*)(srcW[s] + k0),
                (__attribute__((address_space(3))) void*)((char*)Ws + s * 4096 + wave * 1024),
                16, 0, 0);
        __syncthreads();
        #pragma unroll
        for (int kk = 0; kk < KK; ++kk) {
            bf16x8 af[FM], wf[FN];
            #pragma unroll
            for (int i = 0; i < FM; ++i) af[i] = *(const bf16x8*)(As + aoff[i][kk]);
            #pragma unroll
            for (int j = 0; j < FN; ++j) wf[j] = *(const bf16x8*)(Ws + woff[j][kk]);
            #pragma unroll
            for (int i = 0; i < FM; ++i)
                #pragma unroll
                for (int j = 0; j < FN; ++j)
                    acc[i][j] = __builtin_amdgcn_mfma_f32_16x16x32_bf16(af[i], wf[j], acc[i][j], 0, 0, 0);
        }
        __syncthreads();
    }

    int orow0 = bm + wr * WM, ocol0 = bn + wc * WN;
    #pragma unroll
    for (int j = 0; j < FN; ++j) {
        int col = ocol0 + j * 16 + l16;
        float bj = 0.f;
        if constexpr (EPI == 2 || EPI == 3 || EPI == 4) bj = bias[col];
        #pragma unroll
        for (int i = 0; i < FM; ++i) {
            #pragma unroll
            for (int r = 0; r < 4; ++r) {
                int row = orow0 + i * 16 + lk * 4 + r;
                float v = acc[i][j][r];
                if constexpr (EPI == 0) {
                    ((float*)Cout)[(size_t)row * ldc + col] = v;
                } else if constexpr (EPI == 1) {
                    ((ushort*)Cout)[(size_t)row * ldc + col] = f2bf(v);
                } else if constexpr (EPI == 2) {
                    ((ushort*)Cout)[(size_t)row * ldc + col] = f2bf(act_gelu(v + bj));
                } else if constexpr (EPI == 3) {
                    ((float*)Cout)[(size_t)row * ldc + col] = act_softplus(v + bj);
                } else if constexpr (EPI == 4) {
                    ((float*)Cout)[(size_t)row * ldc + col] = v + bj + addsrc[(size_t)row * ldc + col];
                } else {
                    ((float*)Cout)[(size_t)row * ldc + col] = v;
                    if (col < 32) aux[(size_t)row * 32 + col] = f2bf(v);
                }
            }
        }
    }
}

// ---------------- causal depthwise conv (K=4) + silu, bf16 in/out ----------------
__global__ __launch_bounds__(256) void conv_silu_kernel(const ushort* __restrict__ xz,
    const float* __restrict__ cw, const float* __restrict__ cb, ushort* __restrict__ xc)
{
    int idx = blockIdx.x * 256 + threadIdx.x;   // over L*DI
    int d = idx & (DI - 1);
    int t = idx >> 10;
    float acc = cb[d];
    #pragma unroll
    for (int k = 0; k < 4; ++k) {
        int tt = t + k - 3;
        if (tt >= 0) acc = fmaf(cw[d * 4 + k], bf2f(xz[(size_t)tt * (2 * DI) + d]), acc);
    }
    xc[idx] = f2bf(silu_(acc));
}

// ---------------- 3-phase chunked SSM scan ----------------
__global__ __launch_bounds__(256) void scan_chunk_kernel(
    const float* __restrict__ delta, const ushort* __restrict__ u,
    const float* __restrict__ dbc, const float* __restrict__ A_log,
    float* __restrict__ hend, float* __restrict__ aprod)
{
    int n = threadIdx.x & 15, dl = threadIdx.x >> 4;
    int c = blockIdx.x;
    int d = blockIdx.y * 16 + dl;
    float Aval = -__expf(A_log[d * Nst + n]);
    float h = 0.f, ap = 1.f;
    int t0 = c * LC;
    #pragma unroll 4
    for (int t = t0; t < t0 + LC; ++t) {
        float dt_ = delta[(size_t)t * DI + d];
        float u_  = bf2f(u[(size_t)t * DI + d]);
        float b_  = dbc[t * 64 + 32 + n];
        float dA = __expf(dt_ * Aval);
        h = fmaf(dA, h, dt_ * u_ * b_);
        ap *= dA;
    }
    size_t j = (size_t)c * (DI * Nst) + d * Nst + n;
    hend[j] = h;
    aprod[j] = ap;
}

__global__ __launch_bounds__(256) void chunk_prefix_kernel(
    const float* __restrict__ hend, const float* __restrict__ aprod,
    float* __restrict__ hin)
{
    int j = blockIdx.x * 256 + threadIdx.x;   // over DI*Nst
    float h = 0.f;
    for (int c = 0; c < CH; ++c) {
        size_t o = (size_t)c * (DI * Nst) + j;
        hin[o] = h;
        h = fmaf(aprod[o], h, hend[o]);
    }
}

__global__ __launch_bounds__(256) void scan_apply_kernel(
    const float* __restrict__ delta, const ushort* __restrict__ u,
    const float* __restrict__ dbc, const float* __restrict__ A_log,
    const float* __restrict__ Dp, const ushort* __restrict__ xz,
    const float* __restrict__ hin, ushort* __restrict__ y)
{
    int n = threadIdx.x & 15, dl = threadIdx.x >> 4;
    int c = blockIdx.x;
    int d = blockIdx.y * 16 + dl;
    float Aval = -__expf(A_log[d * Nst + n]);
    float Dval = Dp[d];
    float h = hin[(size_t)c * (DI * Nst) + d * Nst + n];
    int t0 = c * LC;
    for (int t = t0; t < t0 + LC; ++t) {
        float dt_ = delta[(size_t)t * DI + d];
        float u_  = bf2f(u[(size_t)t * DI + d]);
        float b_  = dbc[t * 64 + 32 + n];
        float c_  = dbc[t * 64 + 48 + n];
        float dA = __expf(dt_ * Aval);
        h = fmaf(dA, h, dt_ * u_ * b_);
        float py = h * c_;
        py += __shfl_down(py, 8, 16);
        py += __shfl_down(py, 4, 16);
        py += __shfl_down(py, 2, 16);
        py += __shfl_down(py, 1, 16);
        if (n == 0) {
            float z = bf2f(xz[(size_t)t * (2 * DI) + DI + d]);
            y[(size_t)t * DI + d] = f2bf((py + u_ * Dval) * silu_(z));
        }
    }
}

extern "C" void kernel_launch(void* const* d_in, const int* in_sizes, int n_in,
                              void* d_out, int out_size, void* d_ws, size_t ws_size,
                              hipStream_t stream)
{
    const float* hidden     = (const float*)d_in[0];
    const float* ln1_w      = (const float*)d_in[1];
    const float* ln1_b      = (const float*)d_in[2];
    const float* in_proj_w  = (const float*)d_in[3];
    const float* conv_w     = (const float*)d_in[4];
    const float* conv_b     = (const float*)d_in[5];
    const float* x_proj_w   = (const float*)d_in[6];
    const float* dt_proj_w  = (const float*)d_in[7];
    const float* dt_proj_b  = (const float*)d_in[8];
    const float* A_log      = (const float*)d_in[9];
    const float* D_param    = (const float*)d_in[10];
    const float* out_proj_w = (const float*)d_in[11];
    const float* block_norm_w = (const float*)d_in[12];
    const float* norm_f_w   = (const float*)d_in[13];
    const float* ln2_w      = (const float*)d_in[14];
    const float* ln2_b      = (const float*)d_in[15];
    const float* fc1_w      = (const float*)d_in[16];
    const float* fc1_b      = (const float*)d_in[17];
    const float* fc2_w      = (const float*)d_in[18];
    const float* fc2_b      = (const float*)d_in[19];

    char* P = (char*)d_ws;
    auto alloc = [&](size_t bytes) { char* r = P; P += (bytes + 255) & ~(size_t)255; return r; };
    float* h      = (float*)alloc((size_t)L_SEQ * Dm * 4);
    float* res    = (float*)alloc((size_t)L_SEQ * Dm * 4);
    float* hout   = (float*)alloc((size_t)L_SEQ * Dm * 4);
    float* delta  = (float*)alloc((size_t)L_SEQ * DI * 4);
    float* dbc    = (float*)alloc((size_t)L_SEQ * 64 * 4);
    float* hin    = (float*)alloc((size_t)CH * DI * Nst * 4);
    ushort* hn_bf = (ushort*)alloc((size_t)L_SEQ * Dm * 2);
    ushort* xz_bf = (ushort*)alloc((size_t)L_SEQ * 2 * DI * 2);
    ushort* xc_bf = (ushort*)alloc((size_t)L_SEQ * DI * 2);
    ushort* yb_bf = (ushort*)alloc((size_t)L_SEQ * DI * 2);
    ushort* dt_bf = (ushort*)alloc((size_t)L_SEQ * 32 * 2);
    ushort* w_in  = (ushort*)alloc((size_t)NL * 2 * DI * Dm * 2);
    ushort* w_out = (ushort*)alloc((size_t)NL * Dm * DI * 2);
    ushort* w_x   = (ushort*)alloc((size_t)NL * 64 * DI * 2);
    ushort* w_dt  = (ushort*)alloc((size_t)NL * DI * Rr * 2);
    ushort* w_fc1 = (ushort*)alloc((size_t)(4 * Dm) * Dm * 2);
    ushort* w_fc2 = (ushort*)alloc((size_t)Dm * (4 * Dm) * 2);
    float* hend  = h;      // dead during scan
    float* aprod = hout;   // dead until final_merge
    float* out   = (float*)d_out;

    // weight casts (each call; ~10 us total)
    cast_w_kernel<<<(NL * 2 * DI * Dm / 4 + 255) / 256, 256, 0, stream>>>(in_proj_w, w_in, NL * 2 * DI * Dm / 4);
    cast_w_kernel<<<(NL * Dm * DI / 4 + 255) / 256, 256, 0, stream>>>(out_proj_w, w_out, NL * Dm * DI / 4);
    cast_w_kernel<<<(NL * 64 * DI / 4 + 255) / 256, 256, 0, stream>>>(x_proj_w, w_x, NL * 64 * DI / 4);
    cast_w_kernel<<<(NL * DI * Rr / 4 + 255) / 256, 256, 0, stream>>>(dt_proj_w, w_dt, NL * DI * Rr / 4);
    cast_w_kernel<<<(4 * Dm * Dm / 4 + 255) / 256, 256, 0, stream>>>(fc1_w, w_fc1, 4 * Dm * Dm / 4);
    cast_w_kernel<<<(Dm * 4 * Dm / 4 + 255) / 256, 256, 0, stream>>>(fc2_w, w_fc2, Dm * 4 * Dm / 4);

    ln_kernel<<<L_SEQ, 256, 0, stream>>>(hidden, ln1_w, ln1_b, h, nullptr);

    dim3 gscan(CH, DI / 16);
    for (int i = 0; i < NL; ++i) {
        add_rms_kernel<<<L_SEQ, 256, 0, stream>>>(h, i ? res : nullptr, res,
                                                  block_norm_w + i * Dm, hn_bf);
        // in_proj: M=2048 N=2048 K=512 -> bf16 xz
        gemm_mfma<128, 128, 64, 1><<<dim3(2 * DI / 128, L_SEQ / 128), 256, 0, stream>>>(
            hn_bf, Dm, w_in + (size_t)i * 2 * DI * Dm, Dm, xz_bf, 2 * DI, nullptr, nullptr, nullptr);
        conv_silu_kernel<<<(L_SEQ * DI) / 256, 256, 0, stream>>>(
            xz_bf, conv_w + i * DI * Kc, conv_b + i * DI, xc_bf);
        // x_proj: M=2048 N=64 K=1024 -> fp32 dbc + bf16 dt slice
        gemm_mfma<64, 64, 64, 5><<<dim3(1, L_SEQ / 64), 256, 0, stream>>>(
            xc_bf, DI, w_x + (size_t)i * 64 * DI, DI, dbc, 64, nullptr, nullptr, dt_bf);
        // dt_proj: M=2048 N=1024 K=32, softplus+bias -> fp32 delta
        gemm_mfma<64, 64, 32, 3><<<dim3(DI / 64, L_SEQ / 64), 256, 0, stream>>>(
            dt_bf, Rr, w_dt + (size_t)i * DI * Rr, Rr, delta, DI,
            dt_proj_b + i * DI, nullptr, nullptr);
        // chunked scan
        scan_chunk_kernel<<<gscan, 256, 0, stream>>>(delta, xc_bf, dbc,
                                        A_log + (size_t)i * DI * Nst, hend, aprod);
        chunk_prefix_kernel<<<(DI * Nst) / 256, 256, 0, stream>>>(hend, aprod, hin);
        scan_apply_kernel<<<gscan, 256, 0, stream>>>(delta, xc_bf, dbc,
                                        A_log + (size_t)i * DI * Nst,
                                        D_param + i * DI, xz_bf, hin, yb_bf);
        // out_proj: M=2048 N=512 K=1024 -> fp32 h
        gemm_mfma<64, 64, 64, 0><<<dim3(Dm / 64, L_SEQ / 64), 256, 0, stream>>>(
            yb_bf, DI, w_out + (size_t)i * Dm * DI, DI, h, Dm, nullptr, nullptr, nullptr);
    }

    final_merge_kernel<<<L_SEQ, 256, 0, stream>>>(h, res, hidden, norm_f_w, hout);
    ln_kernel<<<L_SEQ, 256, 0, stream>>>(hout, ln2_w, ln2_b, nullptr, hn_bf);
    // fc1: M=2048 N=2048 K=512, bias+gelu -> bf16 t1 (reuse xz_bf)
    gemm_mfma<128, 128, 64, 2><<<dim3(2048 / 128, L_SEQ / 128), 256, 0, stream>>>(
        hn_bf, Dm, w_fc1, Dm, xz_bf, 2048, fc1_b, nullptr, nullptr);
    // fc2: M=2048 N=512 K=2048, bias+add(hout) -> fp32 out
    gemm_mfma<64, 64, 64, 4><<<dim3(Dm / 64, L_SEQ / 64), 256, 0, stream>>>(
        xz_bf, 2048, w_fc2, 2048, out, Dm, fc2_b, hout, nullptr);
}

// Round 4
// 531.226 us; speedup vs baseline: 12.2362x; 1.1622x over previous
//
#include <hip/hip_runtime.h>
#include <hip/hip_bf16.h>
#include <math.h>

#define L_SEQ 2048
#define Dm    512
#define DI    1024
#define Nst   16
#define Kc    4
#define Rr    32
#define NL    4
#define CH    128
#define LC    (L_SEQ / CH)   // 16

typedef __attribute__((ext_vector_type(8))) short bf16x8;
typedef __attribute__((ext_vector_type(4))) float f32x4;

// ---------------- helpers ----------------
__device__ __forceinline__ float act_softplus(float x) {
    return fmaxf(x, 0.f) + log1pf(__expf(-fabsf(x)));
}
__device__ __forceinline__ float act_gelu(float x) {
    float c = 0.7978845608028654f * (x + 0.044715f * x * x * x);
    float t = 1.f - 2.f / (__expf(2.f * c) + 1.f);   // tanh(c)
    return 0.5f * x * (1.f + t);
}
__device__ __forceinline__ float silu_(float x) {
    return x / (1.f + __expf(-x));
}
__device__ __forceinline__ ushort f2bf(float f) {
    union { float f; unsigned u; } c; c.f = f;
    unsigned r = c.u + 0x7fffu + ((c.u >> 16) & 1u);
    return (ushort)(r >> 16);
}
__device__ __forceinline__ float bf2f(ushort u) {
    union { unsigned u; float f; } c; c.u = ((unsigned)u) << 16;
    return c.f;
}

// ---------------- weight cast f32 -> bf16 ----------------
__global__ __launch_bounds__(256) void cast_w_kernel(const float* __restrict__ src,
    ushort* __restrict__ dst, int n4)
{
    int i = blockIdx.x * 256 + threadIdx.x;
    if (i >= n4) return;
    float4 v = ((const float4*)src)[i];
    ushort4 o;
    o.x = f2bf(v.x); o.y = f2bf(v.y); o.z = f2bf(v.z); o.w = f2bf(v.w);
    ((ushort4*)dst)[i] = o;
}

// ---------------- LayerNorm (rows of 512), fp32 or bf16 out ----------------
__global__ __launch_bounds__(256) void ln_kernel(const float* __restrict__ x,
    const float* __restrict__ w, const float* __restrict__ b,
    float* __restrict__ yf, ushort* __restrict__ yb16)
{
    int row = blockIdx.x;
    int i0 = threadIdx.x, i1 = threadIdx.x + 256;
    const float* xr = x + (size_t)row * Dm;
    float v0 = xr[i0], v1 = xr[i1];
    float s = v0 + v1, ss = v0 * v0 + v1 * v1;
    for (int off = 32; off; off >>= 1) { s += __shfl_down(s, off); ss += __shfl_down(ss, off); }
    __shared__ float red[10];
    int wid = threadIdx.x >> 6;
    if ((threadIdx.x & 63) == 0) { red[wid] = s; red[4 + wid] = ss; }
    __syncthreads();
    if (threadIdx.x == 0) {
        float S = red[0] + red[1] + red[2] + red[3];
        float SS = red[4] + red[5] + red[6] + red[7];
        float mu = S * (1.f / Dm);
        float var = SS * (1.f / Dm) - mu * mu;
        red[8] = mu; red[9] = rsqrtf(var + 1e-5f);
    }
    __syncthreads();
    float mu = red[8], rs = red[9];
    float o0 = (v0 - mu) * rs * w[i0] + b[i0];
    float o1 = (v1 - mu) * rs * w[i1] + b[i1];
    if (yf) {
        yf[(size_t)row * Dm + i0] = o0;
        yf[(size_t)row * Dm + i1] = o1;
    } else {
        yb16[(size_t)row * Dm + i0] = f2bf(o0);
        yb16[(size_t)row * Dm + i1] = f2bf(o1);
    }
}

// ---------------- residual add + RMSNorm (sum fp32, rms out bf16) ----------------
__global__ __launch_bounds__(256) void add_rms_kernel(const float* __restrict__ a,
    const float* __restrict__ bsrc, float* __restrict__ sum_out,
    const float* __restrict__ w, ushort* __restrict__ rms_out)
{
    int row = blockIdx.x;
    int i0 = threadIdx.x, i1 = threadIdx.x + 256;
    size_t base = (size_t)row * Dm;
    float v0 = a[base + i0], v1 = a[base + i1];
    if (bsrc) { v0 += bsrc[base + i0]; v1 += bsrc[base + i1]; }
    sum_out[base + i0] = v0; sum_out[base + i1] = v1;
    float ss = v0 * v0 + v1 * v1;
    for (int off = 32; off; off >>= 1) ss += __shfl_down(ss, off);
    __shared__ float red[5];
    if ((threadIdx.x & 63) == 0) red[threadIdx.x >> 6] = ss;
    __syncthreads();
    if (threadIdx.x == 0) red[4] = rsqrtf((red[0] + red[1] + red[2] + red[3]) * (1.f / Dm) + 1e-5f);
    __syncthreads();
    float rs = red[4];
    rms_out[base + i0] = f2bf(v0 * rs * w[i0]);
    rms_out[base + i1] = f2bf(v1 * rs * w[i1]);
}

// ---------------- final: hout = shortcut + RMS(h+res)*w (fp32) ----------------
__global__ __launch_bounds__(256) void final_merge_kernel(const float* __restrict__ h,
    const float* __restrict__ res, const float* __restrict__ shortcut,
    const float* __restrict__ w, float* __restrict__ hout)
{
    int row = blockIdx.x;
    int i0 = threadIdx.x, i1 = threadIdx.x + 256;
    size_t base = (size_t)row * Dm;
    float v0 = h[base + i0] + res[base + i0];
    float v1 = h[base + i1] + res[base + i1];
    float ss = v0 * v0 + v1 * v1;
    for (int off = 32; off; off >>= 1) ss += __shfl_down(ss, off);
    __shared__ float red[5];
    if ((threadIdx.x & 63) == 0) red[threadIdx.x >> 6] = ss;
    __syncthreads();
    if (threadIdx.x == 0) red[4] = rsqrtf((red[0] + red[1] + red[2] + red[3]) * (1.f / Dm) + 1e-5f);
    __syncthreads();
    float rs = red[4];
    hout[base + i0] = shortcut[base + i0] + v0 * rs * w[i0];
    hout[base + i1] = shortcut[base + i1] + v1 * rs * w[i1];
}

// ---------------- MFMA bf16 GEMM: C(M,N) = A(M,K) * W(N,K)^T ----------------
// EPI: 0 = f32 store; 1 = bf16 store; 2 = bias+gelu -> bf16;
//      3 = bias+softplus -> f32; 4 = bias+addsrc -> f32;
//      5 = f32 store (ldc=64) + bf16 copy of cols<32 to aux (ld 32)
template<int BM, int BN, int BK, int EPI>
__global__ __launch_bounds__(256) void gemm_mfma(
    const ushort* __restrict__ A, int lda,
    const ushort* __restrict__ W, int K,
    void* __restrict__ Cout, int ldc,
    const float* __restrict__ bias, const float* __restrict__ addsrc,
    ushort* __restrict__ aux)
{
    constexpr int ROWB  = BK * 2;            // row bytes in LDS tile
    constexpr int SMASK = (ROWB / 16) - 1;   // 16B slots per row - 1
    constexpr int KK    = BK / 32;           // mfma k-chunks per step
    constexpr int WM = BM / 2, WN = BN / 2;
    constexpr int FM = WM / 16, FN = WN / 16;
    constexpr int ISS_A = (BM * ROWB) / 4096;
    constexpr int ISS_W = (BN * ROWB) / 4096;

    __shared__ __align__(16) ushort As[BM * BK];
    __shared__ __align__(16) ushort Ws[BN * BK];

    int tid = threadIdx.x;
    int wave = tid >> 6, lane = tid & 63;
    int wr = wave >> 1, wc = wave & 1;
    int l16 = lane & 15, lk = lane >> 4;
    int bm = blockIdx.y * BM, bn = blockIdx.x * BN;

    // staging source pointers (swizzled source, linear LDS dest)
    const ushort* srcA[ISS_A];
    const ushort* srcW[ISS_W];
    #pragma unroll
    for (int s = 0; s < ISS_A; ++s) {
        int off = s * 4096 + wave * 1024 + lane * 16;   // byte in tile
        int row = off / ROWB;
        int slot = (off % ROWB) >> 4;
        int col = ((slot ^ (row & SMASK)) << 3);        // element
        srcA[s] = A + (size_t)(bm + row) * lda + col;
    }
    #pragma unroll
    for (int s = 0; s < ISS_W; ++s) {
        int off = s * 4096 + wave * 1024 + lane * 16;
        int row = off / ROWB;
        int slot = (off % ROWB) >> 4;
        int col = ((slot ^ (row & SMASK)) << 3);
        srcW[s] = W + (size_t)(bn + row) * K + col;
    }
    // swizzled ds_read element offsets
    int aoff[FM][KK], woff[FN][KK];
    #pragma unroll
    for (int i = 0; i < FM; ++i) {
        int row = wr * WM + i * 16 + l16;
        #pragma unroll
        for (int kk = 0; kk < KK; ++kk)
            aoff[i][kk] = row * BK + ((((kk << 2) | lk) ^ (row & SMASK)) << 3);
    }
    #pragma unroll
    for (int j = 0; j < FN; ++j) {
        int row = wc * WN + j * 16 + l16;
        #pragma unroll
        for (int kk = 0; kk < KK; ++kk)
            woff[j][kk] = row * BK + ((((kk << 2) | lk) ^ (row & SMASK)) << 3);
    }

    f32x4 acc[FM][FN] = {};

    for (int k0 = 0; k0 < K; k0 += BK) {
        #pragma unroll
        for (int s = 0; s < ISS_A; ++s)
            __builtin_amdgcn_global_load_lds(
                (const __attribute__((address_space(1))) void*)(srcA[s] + k0),
                (__attribute__((address_space(3))) void*)((char*)As + s * 4096 + wave * 1024),
                16, 0, 0);
        #pragma unroll
        for (int s = 0; s < ISS_W; ++s)
            __builtin_amdgcn_global_load_lds(
                (const __attribute__((address_space(1))) void*)(srcW[s] + k0),
                (__attribute__((address_space(3))) void*)((char*)Ws + s * 4096 + wave * 1024),
                16, 0, 0);
        __syncthreads();
        #pragma unroll
        for (int kk = 0; kk < KK; ++kk) {
            bf16x8 af[FM], wf[FN];
            #pragma unroll
            for (int i = 0; i < FM; ++i) af[i] = *(const bf16x8*)(As + aoff[i][kk]);
            #pragma unroll
            for (int j = 0; j < FN; ++j) wf[j] = *(const bf16x8*)(Ws + woff[j][kk]);
            #pragma unroll
            for (int i = 0; i < FM; ++i)
                #pragma unroll
                for (int j = 0; j < FN; ++j)
                    acc[i][j] = __builtin_amdgcn_mfma_f32_16x16x32_bf16(af[i], wf[j], acc[i][j], 0, 0, 0);
        }
        __syncthreads();
    }

    int orow0 = bm + wr * WM, ocol0 = bn + wc * WN;
    #pragma unroll
    for (int j = 0; j < FN; ++j) {
        int col = ocol0 + j * 16 + l16;
        float bj = 0.f;
        if constexpr (EPI == 2 || EPI == 3 || EPI == 4) bj = bias[col];
        #pragma unroll
        for (int i = 0; i < FM; ++i) {
            #pragma unroll
            for (int r = 0; r < 4; ++r) {
                int row = orow0 + i * 16 + lk * 4 + r;
                float v = acc[i][j][r];
                if constexpr (EPI == 0) {
                    ((float*)Cout)[(size_t)row * ldc + col] = v;
                } else if constexpr (EPI == 1) {
                    ((ushort*)Cout)[(size_t)row * ldc + col] = f2bf(v);
                } else if constexpr (EPI == 2) {
                    ((ushort*)Cout)[(size_t)row * ldc + col] = f2bf(act_gelu(v + bj));
                } else if constexpr (EPI == 3) {
                    ((float*)Cout)[(size_t)row * ldc + col] = act_softplus(v + bj);
                } else if constexpr (EPI == 4) {
                    ((float*)Cout)[(size_t)row * ldc + col] = v + bj + addsrc[(size_t)row * ldc + col];
                } else {
                    ((float*)Cout)[(size_t)row * ldc + col] = v;
                    if (col < 32) aux[(size_t)row * 32 + col] = f2bf(v);
                }
            }
        }
    }
}

// ---------------- causal depthwise conv (K=4) + silu, bf16 in/out ----------------
__global__ __launch_bounds__(256) void conv_silu_kernel(const ushort* __restrict__ xz,
    const float* __restrict__ cw, const float* __restrict__ cb, ushort* __restrict__ xc)
{
    int idx = blockIdx.x * 256 + threadIdx.x;   // over L*DI
    int d = idx & (DI - 1);
    int t = idx >> 10;
    float acc = cb[d];
    #pragma unroll
    for (int k = 0; k < 4; ++k) {
        int tt = t + k - 3;
        if (tt >= 0) acc = fmaf(cw[d * 4 + k], bf2f(xz[(size_t)tt * (2 * DI) + d]), acc);
    }
    xc[idx] = f2bf(silu_(acc));
}

// ---------------- 3-phase chunked SSM scan, 16 n-states per thread ----------------
// Phase A: thread = (d, chunk); h,aprod for all 16 n in registers.
__global__ __launch_bounds__(256) void scan_chunk_kernel(
    const float* __restrict__ delta, const ushort* __restrict__ u,
    const float* __restrict__ dbc, const float* __restrict__ A_log,
    float* __restrict__ hend, float* __restrict__ aprod)
{
    __shared__ float bs[LC][16];
    int tid = threadIdx.x;
    int c = blockIdx.x;
    int d = blockIdx.y * 256 + tid;
    int t0 = c * LC;
    {   // stage B slice: LC*16 = 256 floats, one per thread
        int tt = tid >> 4, nn = tid & 15;
        bs[tt][nn] = dbc[(size_t)(t0 + tt) * 64 + 32 + nn];
    }
    float A2[16];
    {
        float a[16];
        #pragma unroll
        for (int q = 0; q < 4; ++q)
            *(float4*)(a + q * 4) = ((const float4*)(A_log + (size_t)d * 16))[q];
        #pragma unroll
        for (int n = 0; n < 16; ++n)
            A2[n] = -__expf(a[n]) * 1.44269504f;   // A * log2(e)
    }
    float h[16], ap[16];
    #pragma unroll
    for (int n = 0; n < 16; ++n) { h[n] = 0.f; ap[n] = 1.f; }
    __syncthreads();
    for (int tt = 0; tt < LC; ++tt) {
        int t = t0 + tt;
        float dt_ = delta[(size_t)t * DI + d];
        float du = dt_ * bf2f(u[(size_t)t * DI + d]);
        #pragma unroll
        for (int n = 0; n < 16; ++n) {
            float dA = exp2f(dt_ * A2[n]);
            h[n] = fmaf(dA, h[n], du * bs[tt][n]);
            ap[n] *= dA;
        }
    }
    size_t base = ((size_t)c * DI + d) * 16;
    #pragma unroll
    for (int q = 0; q < 4; ++q) {
        ((float4*)(hend + base))[q]  = *(float4*)(h + q * 4);
        ((float4*)(aprod + base))[q] = *(float4*)(ap + q * 4);
    }
}

// Phase B: sequential over chunks per (d,n); writes h_in IN PLACE over aprod.
__global__ __launch_bounds__(256) void chunk_prefix_kernel(
    const float* __restrict__ hend, float* __restrict__ aprod_hin)
{
    int j = blockIdx.x * 256 + threadIdx.x;   // over DI*16
    float h = 0.f;
    for (int c = 0; c < CH; ++c) {
        size_t o = (size_t)c * (DI * Nst) + j;
        float ap = aprod_hin[o];
        float he = hend[o];
        aprod_hin[o] = h;               // h_in for chunk c
        h = fmaf(ap, h, he);
    }
}

// Phase C: re-scan from h_in; in-register dot with C; gate; store bf16 y.
__global__ __launch_bounds__(256) void scan_apply_kernel(
    const float* __restrict__ delta, const ushort* __restrict__ u,
    const float* __restrict__ dbc, const float* __restrict__ A_log,
    const float* __restrict__ Dp, const ushort* __restrict__ xz,
    const float* __restrict__ hin, ushort* __restrict__ y)
{
    __shared__ float bs[LC][16], cs[LC][16];
    int tid = threadIdx.x;
    int c = blockIdx.x;
    int d = blockIdx.y * 256 + tid;
    int t0 = c * LC;
    #pragma unroll
    for (int i = tid; i < LC * 32; i += 256) {
        int tt = i >> 5, k = i & 31;
        float v = dbc[(size_t)(t0 + tt) * 64 + 32 + k];
        if (k < 16) bs[tt][k] = v; else cs[tt][k - 16] = v;
    }
    float A2[16];
    {
        float a[16];
        #pragma unroll
        for (int q = 0; q < 4; ++q)
            *(float4*)(a + q * 4) = ((const float4*)(A_log + (size_t)d * 16))[q];
        #pragma unroll
        for (int n = 0; n < 16; ++n)
            A2[n] = -__expf(a[n]) * 1.44269504f;
    }
    float h[16];
    size_t base = ((size_t)c * DI + d) * 16;
    #pragma unroll
    for (int q = 0; q < 4; ++q)
        *(float4*)(h + q * 4) = ((const float4*)(hin + base))[q];
    float Dval = Dp[d];
    __syncthreads();
    for (int tt = 0; tt < LC; ++tt) {
        int t = t0 + tt;
        float dt_ = delta[(size_t)t * DI + d];
        float u_  = bf2f(u[(size_t)t * DI + d]);
        float du  = dt_ * u_;
        float acc = 0.f;
        #pragma unroll
        for (int n = 0; n < 16; ++n) {
            float dA = exp2f(dt_ * A2[n]);
            h[n] = fmaf(dA, h[n], du * bs[tt][n]);
            acc = fmaf(h[n], cs[tt][n], acc);
        }
        float z = bf2f(xz[(size_t)t * (2 * DI) + DI + d]);
        y[(size_t)t * DI + d] = f2bf((acc + u_ * Dval) * silu_(z));
    }
}

extern "C" void kernel_launch(void* const* d_in, const int* in_sizes, int n_in,
                              void* d_out, int out_size, void* d_ws, size_t ws_size,
                              hipStream_t stream)
{
    const float* hidden     = (const float*)d_in[0];
    const float* ln1_w      = (const float*)d_in[1];
    const float* ln1_b      = (const float*)d_in[2];
    const float* in_proj_w  = (const float*)d_in[3];
    const float* conv_w     = (const float*)d_in[4];
    const float* conv_b     = (const float*)d_in[5];
    const float* x_proj_w   = (const float*)d_in[6];
    const float* dt_proj_w  = (const float*)d_in[7];
    const float* dt_proj_b  = (const float*)d_in[8];
    const float* A_log      = (const float*)d_in[9];
    const float* D_param    = (const float*)d_in[10];
    const float* out_proj_w = (const float*)d_in[11];
    const float* block_norm_w = (const float*)d_in[12];
    const float* norm_f_w   = (const float*)d_in[13];
    const float* ln2_w      = (const float*)d_in[14];
    const float* ln2_b      = (const float*)d_in[15];
    const float* fc1_w      = (const float*)d_in[16];
    const float* fc1_b      = (const float*)d_in[17];
    const float* fc2_w      = (const float*)d_in[18];
    const float* fc2_b      = (const float*)d_in[19];

    char* P = (char*)d_ws;
    auto alloc = [&](size_t bytes) { char* r = P; P += (bytes + 255) & ~(size_t)255; return r; };
    // h and hout adjacent: their 8MB is dead during the scan and aliased by hend.
    float* h      = (float*)alloc((size_t)L_SEQ * Dm * 4);          // 4MB
    float* hout   = (float*)alloc((size_t)L_SEQ * Dm * 4);          // 4MB (adjacent)
    float* res    = (float*)alloc((size_t)L_SEQ * Dm * 4);
    float* delta  = (float*)alloc((size_t)L_SEQ * DI * 4);
    float* dbc    = (float*)alloc((size_t)L_SEQ * 64 * 4);
    float* aprod  = (float*)alloc((size_t)CH * DI * Nst * 4);       // 8MB; becomes hin
    ushort* hn_bf = (ushort*)alloc((size_t)L_SEQ * Dm * 2);
    ushort* xz_bf = (ushort*)alloc((size_t)L_SEQ * 2 * DI * 2);
    ushort* xc_bf = (ushort*)alloc((size_t)L_SEQ * DI * 2);
    ushort* yb_bf = (ushort*)alloc((size_t)L_SEQ * DI * 2);
    ushort* dt_bf = (ushort*)alloc((size_t)L_SEQ * 32 * 2);
    ushort* w_in  = (ushort*)alloc((size_t)2 * DI * Dm * 2);        // per-layer
    ushort* w_out = (ushort*)alloc((size_t)Dm * DI * 2);
    ushort* w_x   = (ushort*)alloc((size_t)64 * DI * 2);
    ushort* w_dt  = (ushort*)alloc((size_t)DI * Rr * 2);
    ushort* w_fc1 = (ushort*)alloc((size_t)(4 * Dm) * Dm * 2);
    ushort* w_fc2 = (ushort*)alloc((size_t)Dm * (4 * Dm) * 2);
    float* hend = h;      // 8MB over h+hout, both dead during scan
    float* out  = (float*)d_out;

    cast_w_kernel<<<(4 * Dm * Dm / 4 + 255) / 256, 256, 0, stream>>>(fc1_w, w_fc1, 4 * Dm * Dm / 4);
    cast_w_kernel<<<(Dm * 4 * Dm / 4 + 255) / 256, 256, 0, stream>>>(fc2_w, w_fc2, Dm * 4 * Dm / 4);

    ln_kernel<<<L_SEQ, 256, 0, stream>>>(hidden, ln1_w, ln1_b, h, nullptr);

    dim3 gscan(CH, DI / 256);
    for (int i = 0; i < NL; ++i) {
        // per-layer weight casts into small reused buffers
        cast_w_kernel<<<(2 * DI * Dm / 4 + 255) / 256, 256, 0, stream>>>(
            in_proj_w + (size_t)i * 2 * DI * Dm, w_in, 2 * DI * Dm / 4);
        cast_w_kernel<<<(Dm * DI / 4 + 255) / 256, 256, 0, stream>>>(
            out_proj_w + (size_t)i * Dm * DI, w_out, Dm * DI / 4);
        cast_w_kernel<<<(64 * DI / 4 + 255) / 256, 256, 0, stream>>>(
            x_proj_w + (size_t)i * 64 * DI, w_x, 64 * DI / 4);
        cast_w_kernel<<<(DI * Rr / 4 + 255) / 256, 256, 0, stream>>>(
            dt_proj_w + (size_t)i * DI * Rr, w_dt, DI * Rr / 4);

        add_rms_kernel<<<L_SEQ, 256, 0, stream>>>(h, i ? res : nullptr, res,
                                                  block_norm_w + i * Dm, hn_bf);
        // in_proj: M=2048 N=2048 K=512 -> bf16 xz
        gemm_mfma<128, 128, 64, 1><<<dim3(2 * DI / 128, L_SEQ / 128), 256, 0, stream>>>(
            hn_bf, Dm, w_in, Dm, xz_bf, 2 * DI, nullptr, nullptr, nullptr);
        conv_silu_kernel<<<(L_SEQ * DI) / 256, 256, 0, stream>>>(
            xz_bf, conv_w + i * DI * Kc, conv_b + i * DI, xc_bf);
        // x_proj: M=2048 N=64 K=1024 -> fp32 dbc + bf16 dt slice
        gemm_mfma<64, 64, 64, 5><<<dim3(1, L_SEQ / 64), 256, 0, stream>>>(
            xc_bf, DI, w_x, DI, dbc, 64, nullptr, nullptr, dt_bf);
        // dt_proj: M=2048 N=1024 K=32, softplus+bias -> fp32 delta
        gemm_mfma<64, 64, 32, 3><<<dim3(DI / 64, L_SEQ / 64), 256, 0, stream>>>(
            dt_bf, Rr, w_dt, Rr, delta, DI, dt_proj_b + i * DI, nullptr, nullptr);
        // chunked scan
        scan_chunk_kernel<<<gscan, 256, 0, stream>>>(delta, xc_bf, dbc,
                                        A_log + (size_t)i * DI * Nst, hend, aprod);
        chunk_prefix_kernel<<<(DI * Nst) / 256, 256, 0, stream>>>(hend, aprod);
        scan_apply_kernel<<<gscan, 256, 0, stream>>>(delta, xc_bf, dbc,
                                        A_log + (size_t)i * DI * Nst,
                                        D_param + i * DI, xz_bf, aprod, yb_bf);
        // out_proj: M=2048 N=512 K=1024 -> fp32 h
        gemm_mfma<64, 64, 64, 0><<<dim3(Dm / 64, L_SEQ / 64), 256, 0, stream>>>(
            yb_bf, DI, w_out, DI, h, Dm, nullptr, nullptr, nullptr);
    }

    final_merge_kernel<<<L_SEQ, 256, 0, stream>>>(h, res, hidden, norm_f_w, hout);
    ln_kernel<<<L_SEQ, 256, 0, stream>>>(hout, ln2_w, ln2_b, nullptr, hn_bf);
    // fc1: M=2048 N=2048 K=512, bias+gelu -> bf16 (reuse xz_bf)
    gemm_mfma<128, 128, 64, 2><<<dim3(2048 / 128, L_SEQ / 128), 256, 0, stream>>>(
        hn_bf, Dm, w_fc1, Dm, xz_bf, 2048, fc1_b, nullptr, nullptr);
    // fc2: M=2048 N=512 K=2048, bias+add(hout) -> fp32 out
    gemm_mfma<64, 64, 64, 4><<<dim3(Dm / 64, L_SEQ / 64), 256, 0, stream>>>(
        xz_bf, 2048, w_fc2, 2048, out, Dm, fc2_b, hout, nullptr);
}